// Round 9
// baseline (590.743 us; speedup 1.0000x reference)
//
#include <hip/hip_runtime.h>
#include <math.h>

// ---------------------------------------------------------------------------
// MultiTaskGAT: 2x GATConv(8 heads x 32ch, concat) + 4 task heads (1 head)
// N=50000 nodes, E=800000 edges (+N self loops), F_IN=128, DH=256.
//
// R4: GEMMs -> bf16 MFMA hi/lo split.
// R6: alphas folded into GEMM B-columns; log_softmax fused into task gather.
// R8: CSR rows padded to x4; shuffle-based scan kernel.
// R9: per-wave CSR index preload (1 coalesced load + v_readlane).
// R11: edge weights fused into gathers (ew kernels/csrd deleted).
// R16: chunk-hoisted edge weights -> per-wave LDS (conflict-free, stride 68).
// R17: 2-deep software pipeline in both gathers: group e+8's row loads are
//     issued BEFORE group e's FMAs (addresses need only idxv); group 0's
//     loads issue before weight production so the exp/LDS chain overlaps.
//     Task LSE epilogue drops the max-subtraction (logits O(10), f32-safe):
//     removes the 4-var max tree (24 shfl_xor) and the m->exp serialization.
// ---------------------------------------------------------------------------

#define NEG_SLOPE 0.2f

typedef short s8v __attribute__((ext_vector_type(8)));
typedef short s4v __attribute__((ext_vector_type(4)));
typedef float f4v __attribute__((ext_vector_type(4)));

__device__ __forceinline__ short f2bf(float x) {
    unsigned u = __float_as_uint(x);
    u += 0x7fffu + ((u >> 16) & 1u);
    return (short)(u >> 16);
}
__device__ __forceinline__ float bf2f(short b) {
    return __uint_as_float(((unsigned)(unsigned short)b) << 16);
}
__device__ __forceinline__ void split2(float x, short& h, short& l) {
    h = f2bf(x);
    l = f2bf(x - bf2f(h));
}
__device__ __forceinline__ float4 bf4_to_f4(s4v v) {
    return make_float4(bf2f(v[0]), bf2f(v[1]), bf2f(v[2]), bf2f(v[3]));
}
// leaky_relu(x) == max(x, 0.2x) for slope<1
__device__ __forceinline__ float leaky(float x) {
    return fmaxf(x, NEG_SLOPE * x);
}

// ---------------- CSR build ----------------

__global__ void init_kernel(int* __restrict__ deg, int* __restrict__ cursor, int n) {
    int i = blockIdx.x * blockDim.x + threadIdx.x;
    if (i < n) { deg[i] = 1; cursor[i] = 0; }   // deg starts at 1: self loop
}

__global__ void count_kernel(const int* __restrict__ dst, int* __restrict__ deg, int E) {
    int i = blockIdx.x * blockDim.x + threadIdx.x;
    if (i < E) atomicAdd(&deg[dst[i]], 1);
}

// scan of padded degrees ((deg+3)&~3) — shuffle-based, 3 barriers/iter
__global__ __launch_bounds__(1024) void scan_kernel(const int* __restrict__ deg,
                                                    int* __restrict__ rowstart, int n) {
    __shared__ int wsum[16];
    __shared__ int carry_sh;
    int lane = threadIdx.x & 63, wv = threadIdx.x >> 6;
    if (threadIdx.x == 0) { carry_sh = 0; rowstart[0] = 0; }
    __syncthreads();
    for (int base = 0; base < n; base += 8192) {
        int vals[8];
        int sum = 0;
        int i0 = base + threadIdx.x * 8;
        #pragma unroll
        for (int j = 0; j < 8; ++j) {
            int i = i0 + j;
            int v = (i < n) ? ((deg[i] + 3) & ~3) : 0;
            sum += v;
            vals[j] = sum;               // local inclusive
        }
        int incl = sum;
        #pragma unroll
        for (int off = 1; off < 64; off <<= 1) {
            int t = __shfl_up(incl, off);
            if (lane >= off) incl += t;
        }
        if (lane == 63) wsum[wv] = incl;
        __syncthreads();
        if (wv == 0) {
            int s = (lane < 16) ? wsum[lane] : 0;
            #pragma unroll
            for (int off = 1; off < 16; off <<= 1) {
                int t = __shfl_up(s, off);
                if (lane >= off) s += t;
            }
            if (lane < 16) wsum[lane] = s;
        }
        __syncthreads();
        int wexcl = (wv == 0) ? 0 : wsum[wv - 1];
        int excl = carry_sh + wexcl + (incl - sum);
        #pragma unroll
        for (int j = 0; j < 8; ++j) {
            int i = i0 + j;
            if (i < n) rowstart[i + 1] = excl + vals[j];
        }
        __syncthreads();
        if (threadIdx.x == 0) carry_sh += wsum[15];
        __syncthreads();
    }
}

__global__ void scatter_kernel(const int* __restrict__ src, const int* __restrict__ dst,
                               const int* __restrict__ rowstart, int* __restrict__ cursor,
                               int* __restrict__ csr, int E, int n) {
    int i = blockIdx.x * blockDim.x + threadIdx.x;
    if (i >= E + n) return;
    int s, d;
    if (i < E) { s = src[i]; d = dst[i]; }
    else       { s = d = i - E; }          // self loop
    int p = atomicAdd(&cursor[d], 1);
    csr[rowstart[d] + p] = s;
}

// ---------------- bf16 conversions / splits ----------------

__global__ void tobf_kernel(const float* __restrict__ A, short* __restrict__ Ah, int n4) {
    int i = blockIdx.x * blockDim.x + threadIdx.x;
    if (i >= n4) return;
    float4 v = ((const float4*)A)[i];
    s4v hv = {f2bf(v.x), f2bf(v.y), f2bf(v.z), f2bf(v.w)};
    ((s4v*)Ah)[i] = hv;
}

// B[K][Nc] fp32 -> Bt[n][k] bf16 hi/lo (k-contiguous for MFMA B-fragments)
__global__ void split_bt_kernel(const float* __restrict__ B, short* __restrict__ Bh,
                                short* __restrict__ Bl, int K, int Nc, int kshift) {
    int idx = blockIdx.x * blockDim.x + threadIdx.x;
    if (idx >= Nc * K) return;
    int n = idx >> kshift;          // K is a power of two (128/256)
    int k = idx & (K - 1);
    float v = B[(size_t)k * Nc + n];
    short h, l; split2(v, h, l);
    Bh[idx] = h;
    Bl[idx] = l;
}

// fold alphas into extra B-columns: col Nfeat+j (j<8: a_s head j, j>=8: a_d)
__global__ void fold_alpha8_kernel(const float* __restrict__ W,
                                   const float* __restrict__ a_s, const float* __restrict__ a_d,
                                   short* __restrict__ Bth, short* __restrict__ Btl,
                                   int K, int Nfeat) {
    int idx = blockIdx.x * blockDim.x + threadIdx.x;
    if (idx >= K * 16) return;
    int j = idx / K, k = idx % K;
    int h = j & 7;
    const float* av = ((j < 8) ? a_s : a_d) + h * 32;
    const float* wp = W + (size_t)k * 256 + h * 32;
    float s = 0.f;
    #pragma unroll
    for (int c = 0; c < 32; ++c) s += wp[c] * av[c];
    short hi, lo; split2(s, hi, lo);
    size_t off = (size_t)(Nfeat + j) * K + k;
    Bth[off] = hi; Btl[off] = lo;
}

// task version: 4 tasks, PADDED segments over 224 channels, K=256.
// segment starts {0,12,44,104}, padded lengths {12,32,60,120} (pads hold
// zero W and zero alpha -> contribute 0).
__global__ void fold_alpha4_kernel(const float* __restrict__ Wcat,
                                   const float* __restrict__ ascat, const float* __restrict__ adcat,
                                   short* __restrict__ Bth, short* __restrict__ Btl) {
    int idx = blockIdx.x * blockDim.x + threadIdx.x;
    if (idx >= 256 * 8) return;
    int j = idx >> 8, k = idx & 255;
    const int CO[4] = {0, 12, 44, 104};
    const int CL[4] = {12, 32, 60, 120};
    int t = j & 3;
    const float* av = ((j < 4) ? ascat : adcat) + CO[t];
    const float* wp = Wcat + (size_t)k * 224 + CO[t];
    float s = 0.f;
    for (int c = 0; c < CL[t]; ++c) s += wp[c] * av[c];
    short hi, lo; split2(s, hi, lo);
    size_t off = (size_t)(224 + j) * 256 + k;
    Bth[off] = hi; Btl[off] = lo;
}

// ---------------- bf16 MFMA GEMM + fused alpha output ----------------------

#define MB 128
#define NB 64
#define KS 32

__global__ __launch_bounds__(256) void gemm_mfma_kernel(
        const short* __restrict__ Ah_g,
        const short* __restrict__ Bth_g, const short* __restrict__ Btl_g,
        short* __restrict__ Cb, int cb_stride,
        float* __restrict__ als, float* __restrict__ ald, int nsplit,
        int M, int K, int Nfeat, int NcExt) {
    __shared__ __align__(16) short Ah[MB][40];
    __shared__ __align__(16) short Bh[NB][40];
    __shared__ __align__(16) short Bl[NB][40];

    int t = threadIdx.x;
    int lane = t & 63, w = t >> 6;
    int quad = lane >> 4, l16 = lane & 15;
    int row0 = blockIdx.y * MB, col0 = blockIdx.x * NB;

    f4v acc[2][4];
    #pragma unroll
    for (int mt = 0; mt < 2; ++mt)
        #pragma unroll
        for (int nt = 0; nt < 4; ++nt)
            acc[mt][nt] = (f4v){0.f, 0.f, 0.f, 0.f};

    for (int k0 = 0; k0 < K; k0 += KS) {
        __syncthreads();
        #pragma unroll
        for (int i = 0; i < 2; ++i) {
            int u = i * 256 + t;
            int r = u >> 2, kk = (u & 3) * 8;
            int gr = row0 + r;
            s8v vh = {0, 0, 0, 0, 0, 0, 0, 0};
            if (gr < M) vh = *(const s8v*)(Ah_g + (size_t)gr * K + k0 + kk);
            *(s8v*)&Ah[r][kk] = vh;
        }
        {
            int n = t >> 2, kk = (t & 3) * 8;
            int gc = col0 + n;
            s8v vh = {0, 0, 0, 0, 0, 0, 0, 0};
            s8v vl = {0, 0, 0, 0, 0, 0, 0, 0};
            if (gc < NcExt) {
                vh = *(const s8v*)(Bth_g + (size_t)gc * K + k0 + kk);
                vl = *(const s8v*)(Btl_g + (size_t)gc * K + k0 + kk);
            }
            *(s8v*)&Bh[n][kk] = vh;
            *(s8v*)&Bl[n][kk] = vl;
        }
        __syncthreads();

        int kb = quad * 8;
        s8v a_f[2], b_h[4], b_l[4];
        #pragma unroll
        for (int mt = 0; mt < 2; ++mt) {
            int r = w * 32 + mt * 16 + l16;
            a_f[mt] = *(const s8v*)&Ah[r][kb];
        }
        #pragma unroll
        for (int nt = 0; nt < 4; ++nt) {
            int c = nt * 16 + l16;
            b_h[nt] = *(const s8v*)&Bh[c][kb];
            b_l[nt] = *(const s8v*)&Bl[c][kb];
        }
        #pragma unroll
        for (int mt = 0; mt < 2; ++mt)
            #pragma unroll
            for (int nt = 0; nt < 4; ++nt) {
                acc[mt][nt] = __builtin_amdgcn_mfma_f32_16x16x32_bf16(
                    a_f[mt], b_h[nt], acc[mt][nt], 0, 0, 0);
                acc[mt][nt] = __builtin_amdgcn_mfma_f32_16x16x32_bf16(
                    a_f[mt], b_l[nt], acc[mt][nt], 0, 0, 0);
            }
    }

    // epilogue: C/D layout col=lane&15, row=quad*4+reg
    #pragma unroll
    for (int mt = 0; mt < 2; ++mt) {
        #pragma unroll
        for (int nt = 0; nt < 4; ++nt) {
            int gc = col0 + nt * 16 + l16;
            if (gc >= NcExt) continue;
            #pragma unroll
            for (int r = 0; r < 4; ++r) {
                int gr = row0 + w * 32 + mt * 16 + quad * 4 + r;
                if (gr >= M) continue;
                float v = acc[mt][nt][r];
                if (gc < Nfeat) {
                    Cb[(size_t)gr * cb_stride + gc] = f2bf(v);
                } else {
                    int j = gc - Nfeat;
                    if (j < nsplit)            als[(size_t)gr * nsplit + j] = v;
                    else if (j < 2 * nsplit)   ald[(size_t)gr * nsplit + (j - nsplit)] = v;
                }
            }
        }
    }
}

// ---------------- GAT gather (8 heads x 32 ch), one wave per dst -----------
// Chunk-hoisted LDS weights (R16) + 2-deep row-load pipeline (R17):
// group e+8's loads issue before group e's FMAs.

#define EWS 68   // LDS row stride (dwords): conflict-free b128 reads

__global__ __launch_bounds__(256) void gat_gather_kernel(
        const short* __restrict__ hb,
        const float* __restrict__ als, const float* __restrict__ ald,
        const int* __restrict__ rowstart, const int* __restrict__ csr,
        const float* __restrict__ bias, short* __restrict__ oh, int n, int elu) {
    __shared__ __align__(16) float ewl_all[4][8 * EWS];
    int wv   = threadIdx.x >> 6;
    int lane = threadIdx.x & 63;
    float* ewl = ewl_all[wv];
    int wid  = blockIdx.x * 4 + wv;
    if (wid >= n) return;
    int row = rowstart[wid];
    int pdeg = rowstart[wid + 1] - row;
    int hp = lane >> 3;              // consumer head
    int ch = lane * 4;
    const int* cp = csr + row;
    float aldf[8];
    #pragma unroll
    for (int h = 0; h < 8; ++h) aldf[h] = ald[(size_t)wid * 8 + h];

    float4 acc = {0.f, 0.f, 0.f, 0.f};
    float wsum = 0.f;
    for (int base = 0; base < pdeg; base += 64) {
        int cnt = min(pdeg - base, 64);
        int idxv = -1;
        if (lane < cnt) idxv = cp[base + lane];
        // prefetch group 0 rows (depends only on idxv)
        int siA[8]; s4v hvA[8];
        if (cnt >= 8) {
            #pragma unroll
            for (int i = 0; i < 8; ++i) {
                int r = __builtin_amdgcn_readlane(idxv, i);
                siA[i] = r < 0 ? 0 : r;
            }
            #pragma unroll
            for (int i = 0; i < 8; ++i)
                hvA[i] = *(const s4v*)(hb + (size_t)siA[i] * 256 + ch);
        }
        {   // produce this chunk's weights (overlaps group-0 loads)
            int sidx = idxv < 0 ? 0 : idxv;
            float4 a0 = *(const float4*)(als + (size_t)sidx * 8);
            float4 a1 = *(const float4*)(als + (size_t)sidx * 8 + 4);
            float av[8] = {a0.x, a0.y, a0.z, a0.w, a1.x, a1.y, a1.z, a1.w};
            #pragma unroll
            for (int h = 0; h < 8; ++h) {
                float w = __expf(leaky(av[h] + aldf[h]));
                if (idxv < 0) w = 0.f;
                ewl[h * EWS + lane] = w;
            }
        }
        int e = 0;
        if (cnt >= 8) {
            for (; e + 16 <= cnt; e += 8) {
                int siB[8]; s4v hvB[8];
                #pragma unroll
                for (int i = 0; i < 8; ++i) {
                    int r = __builtin_amdgcn_readlane(idxv, e + 8 + i);
                    siB[i] = r < 0 ? 0 : r;
                }
                #pragma unroll
                for (int i = 0; i < 8; ++i)
                    hvB[i] = *(const s4v*)(hb + (size_t)siB[i] * 256 + ch);
                float4 wa = *(const float4*)&ewl[hp * EWS + e];
                float4 wb = *(const float4*)&ewl[hp * EWS + e + 4];
                float w[8] = {wa.x, wa.y, wa.z, wa.w, wb.x, wb.y, wb.z, wb.w};
                #pragma unroll
                for (int i = 0; i < 8; ++i) {
                    float4 h = bf4_to_f4(hvA[i]);
                    acc.x += w[i] * h.x; acc.y += w[i] * h.y;
                    acc.z += w[i] * h.z; acc.w += w[i] * h.w;
                    wsum += w[i];
                }
                #pragma unroll
                for (int i = 0; i < 8; ++i) hvA[i] = hvB[i];
            }
            {   // last full group
                float4 wa = *(const float4*)&ewl[hp * EWS + e];
                float4 wb = *(const float4*)&ewl[hp * EWS + e + 4];
                float w[8] = {wa.x, wa.y, wa.z, wa.w, wb.x, wb.y, wb.z, wb.w};
                #pragma unroll
                for (int i = 0; i < 8; ++i) {
                    float4 h = bf4_to_f4(hvA[i]);
                    acc.x += w[i] * h.x; acc.y += w[i] * h.y;
                    acc.z += w[i] * h.z; acc.w += w[i] * h.w;
                    wsum += w[i];
                }
                e += 8;
            }
        }
        if (e < cnt) {                   // 4-edge tail, at most once
            int si[4];
            #pragma unroll
            for (int i = 0; i < 4; ++i) {
                int r = __builtin_amdgcn_readlane(idxv, e + i);
                si[i] = r < 0 ? 0 : r;
            }
            s4v hv[4];
            #pragma unroll
            for (int i = 0; i < 4; ++i)
                hv[i] = *(const s4v*)(hb + (size_t)si[i] * 256 + ch);
            float4 wa = *(const float4*)&ewl[hp * EWS + e];
            float w[4] = {wa.x, wa.y, wa.z, wa.w};
            #pragma unroll
            for (int i = 0; i < 4; ++i) {
                float4 h = bf4_to_f4(hv[i]);
                acc.x += w[i] * h.x; acc.y += w[i] * h.y;
                acc.z += w[i] * h.z; acc.w += w[i] * h.w;
                wsum += w[i];
            }
        }
    }
    float inv = 1.f / (wsum + 1e-16f);
    float4 b4 = *(const float4*)(bias + ch);
    float v[4] = {acc.x * inv + b4.x, acc.y * inv + b4.y,
                  acc.z * inv + b4.z, acc.w * inv + b4.w};
    if (elu) {
        #pragma unroll
        for (int j = 0; j < 4; ++j)
            v[j] = (v[j] > 0.f) ? v[j] : __expf(v[j]) - 1.f;
    }
    s4v hvo = {f2bf(v[0]), f2bf(v[1]), f2bf(v[2]), f2bf(v[3])};
    *(s4v*)(oh + (size_t)wid * 256 + ch) = hvo;
}

// ---------------- task-head packing (Wcat, bcat, ascat, adcat) -------------
// PADDED 224-channel layout: segments at {0,12,44,104}, pad cols 42,43 zero.

__global__ void pack_w_kernel(const float* __restrict__ wTL, const float* __restrict__ wYL,
                              const float* __restrict__ wTS, const float* __restrict__ wTZ,
                              const float* __restrict__ bTL, const float* __restrict__ bYL,
                              const float* __restrict__ bTS, const float* __restrict__ bTZ,
                              const float* __restrict__ asTL, const float* __restrict__ asYL,
                              const float* __restrict__ asTS, const float* __restrict__ asTZ,
                              const float* __restrict__ adTL, const float* __restrict__ adYL,
                              const float* __restrict__ adTS, const float* __restrict__ adTZ,
                              float* __restrict__ Wcat, float* __restrict__ bcat,
                              float* __restrict__ ascat, float* __restrict__ adcat) {
    int idx = blockIdx.x * blockDim.x + threadIdx.x;
    if (idx < 256 * 224) {
        int r = idx / 224, c = idx % 224;
        float v = 0.f;
        if (c < 12)       v = wTL[r * 12 + c];
        else if (c < 42)  v = wYL[r * 30 + (c - 12)];
        else if (c < 44)  v = 0.f;
        else if (c < 104) v = wTS[r * 60 + (c - 44)];
        else              v = wTZ[r * 120 + (c - 104)];
        Wcat[idx] = v;
    }
    if (idx < 224) {
        float b = 0.f, as_ = 0.f, ad_ = 0.f;
        if (idx < 12)       { b = bTL[idx];       as_ = asTL[idx];       ad_ = adTL[idx]; }
        else if (idx < 42)  { b = bYL[idx - 12];  as_ = asYL[idx - 12];  ad_ = adYL[idx - 12]; }
        else if (idx < 44)  { }
        else if (idx < 104) { b = bTS[idx - 44];  as_ = asTS[idx - 44];  ad_ = adTS[idx - 44]; }
        else                { b = bTZ[idx - 104]; as_ = asTZ[idx - 104]; ad_ = adTZ[idx - 104]; }
        bcat[idx]  = b;
        ascat[idx] = as_;
        adcat[idx] = ad_;
    }
}

// ---------------- 4-task gather + fused log_softmax (register-only) --------
// Padded 224-ch layout: lane*4 channels lie in exactly ONE task segment.
// Chunk-hoisted LDS weights + 2-deep pipeline. LSE without max-subtraction
// (logits O(10): exp/log exact in f32 to well below absmax tolerance).

__device__ __forceinline__ float sel4(int t, float v0, float v1, float v2, float v3) {
    return (t == 0) ? v0 : (t == 1) ? v1 : (t == 2) ? v2 : v3;
}

__global__ __launch_bounds__(256) void task_gather_ls_kernel(
        const short* __restrict__ htb,
        const float* __restrict__ ast, const float* __restrict__ adt,
        const int* __restrict__ rowstart, const int* __restrict__ csr,
        const float* __restrict__ bcat, float* __restrict__ out, int n) {
    __shared__ __align__(16) float ewl_all[4][4 * EWS];
    int wv   = threadIdx.x >> 6;
    int lane = threadIdx.x & 63;
    float* ewl = ewl_all[wv];
    int wid  = blockIdx.x * 4 + wv;
    if (wid >= n) return;
    int row = rowstart[wid];
    int pdeg = rowstart[wid + 1] - row;
    int ch0 = (lane < 56) ? lane * 4 : 0;
    int t = (lane < 3) ? 0 : (lane < 11) ? 1 : (lane < 26) ? 2 : 3;
    int COp = (t == 0) ? 0 : (t == 1) ? 12 : (t == 2) ? 44 : 104;   // padded start
    int COr = (t == 0) ? 0 : (t == 1) ? 12 : (t == 2) ? 42 : 102;   // real out offset
    int CLr = (t == 0) ? 12 : (t == 1) ? 30 : (t == 2) ? 60 : 120;  // real length
    bool valj[4];
    #pragma unroll
    for (int j = 0; j < 4; ++j)
        valj[j] = (unsigned)(ch0 + j - COp) < (unsigned)CLr;

    const int* cp = csr + row;
    float adtf[4];
    #pragma unroll
    for (int q = 0; q < 4; ++q) adtf[q] = adt[(size_t)wid * 4 + q];

    float acc[4] = {0.f, 0.f, 0.f, 0.f};
    float wsv = 0.f;
    for (int base = 0; base < pdeg; base += 64) {
        int cnt = min(pdeg - base, 64);
        int idxv = -1;
        if (lane < cnt) idxv = cp[base + lane];
        // prefetch group 0 rows
        int siA[8]; s4v hvA[8];
        if (cnt >= 8) {
            #pragma unroll
            for (int i = 0; i < 8; ++i) {
                int r = __builtin_amdgcn_readlane(idxv, i);
                siA[i] = r < 0 ? 0 : r;
            }
            #pragma unroll
            for (int i = 0; i < 8; ++i)
                hvA[i] = *(const s4v*)(htb + (size_t)siA[i] * 224 + ch0);
        }
        {   // produce this chunk's weights (overlaps group-0 loads)
            int sidx = idxv < 0 ? 0 : idxv;
            float4 a = *(const float4*)(ast + (size_t)sidx * 4);
            float av[4] = {a.x, a.y, a.z, a.w};
            #pragma unroll
            for (int q = 0; q < 4; ++q) {
                float w = __expf(leaky(av[q] + adtf[q]));
                if (idxv < 0) w = 0.f;
                ewl[q * EWS + lane] = w;
            }
        }
        int e = 0;
        if (cnt >= 8) {
            for (; e + 16 <= cnt; e += 8) {
                int siB[8]; s4v hvB[8];
                #pragma unroll
                for (int i = 0; i < 8; ++i) {
                    int r = __builtin_amdgcn_readlane(idxv, e + 8 + i);
                    siB[i] = r < 0 ? 0 : r;
                }
                #pragma unroll
                for (int i = 0; i < 8; ++i)
                    hvB[i] = *(const s4v*)(htb + (size_t)siB[i] * 224 + ch0);
                float4 wa = *(const float4*)&ewl[t * EWS + e];
                float4 wb = *(const float4*)&ewl[t * EWS + e + 4];
                float w[8] = {wa.x, wa.y, wa.z, wa.w, wb.x, wb.y, wb.z, wb.w};
                #pragma unroll
                for (int i = 0; i < 8; ++i) {
                    float4 h = bf4_to_f4(hvA[i]);
                    acc[0] += w[i] * h.x; acc[1] += w[i] * h.y;
                    acc[2] += w[i] * h.z; acc[3] += w[i] * h.w;
                    wsv += w[i];
                }
                #pragma unroll
                for (int i = 0; i < 8; ++i) hvA[i] = hvB[i];
            }
            {   // last full group
                float4 wa = *(const float4*)&ewl[t * EWS + e];
                float4 wb = *(const float4*)&ewl[t * EWS + e + 4];
                float w[8] = {wa.x, wa.y, wa.z, wa.w, wb.x, wb.y, wb.z, wb.w};
                #pragma unroll
                for (int i = 0; i < 8; ++i) {
                    float4 h = bf4_to_f4(hvA[i]);
                    acc[0] += w[i] * h.x; acc[1] += w[i] * h.y;
                    acc[2] += w[i] * h.z; acc[3] += w[i] * h.w;
                    wsv += w[i];
                }
                e += 8;
            }
        }
        if (e < cnt) {                   // 4-edge tail, at most once
            int si[4];
            #pragma unroll
            for (int i = 0; i < 4; ++i) {
                int r = __builtin_amdgcn_readlane(idxv, e + i);
                si[i] = r < 0 ? 0 : r;
            }
            s4v hv[4];
            #pragma unroll
            for (int i = 0; i < 4; ++i)
                hv[i] = *(const s4v*)(htb + (size_t)si[i] * 224 + ch0);
            float4 wa = *(const float4*)&ewl[t * EWS + e];
            float w[4] = {wa.x, wa.y, wa.z, wa.w};
            #pragma unroll
            for (int i = 0; i < 4; ++i) {
                float4 h = bf4_to_f4(hv[i]);
                acc[0] += w[i] * h.x; acc[1] += w[i] * h.y;
                acc[2] += w[i] * h.z; acc[3] += w[i] * h.w;
                wsv += w[i];
            }
        }
    }
    float inv = 1.f / (wsv + 1e-16f);

    // normalized logits; direct LSE (no max-subtraction)
    float vout[4];
    float sacc = 0.f;
    #pragma unroll
    for (int j = 0; j < 4; ++j) {
        float v = 0.f;
        if (valj[j]) { v = acc[j] * inv + bcat[ch0 + j]; sacc += __expf(v); }
        vout[j] = v;
    }
    float s0 = (t == 0) ? sacc : 0.f;
    float s1 = (t == 1) ? sacc : 0.f;
    float s2 = (t == 2) ? sacc : 0.f;
    float s3 = (t == 3) ? sacc : 0.f;
    #pragma unroll
    for (int off = 1; off < 64; off <<= 1) {
        s0 += __shfl_xor(s0, off);
        s1 += __shfl_xor(s1, off);
        s2 += __shfl_xor(s2, off);
        s3 += __shfl_xor(s3, off);
    }
    float st = sel4(t, s0, s1, s2, s3);
    float lse = __logf(st);
    #pragma unroll
    for (int j = 0; j < 4; ++j)
        if (valj[j])
            out[(size_t)COr * n + (size_t)wid * CLr + (ch0 + j - COp)] = vout[j] - lse;
}

// ---------------- launcher ----------------

extern "C" void kernel_launch(void* const* d_in, const int* in_sizes, int n_in,
                              void* d_out, int out_size, void* d_ws, size_t ws_size,
                              hipStream_t stream) {
    const float* x   = (const float*)d_in[0];
    const int*   ei  = (const int*)d_in[1];
    const float* W1  = (const float*)d_in[2];
    const float* a1s = (const float*)d_in[3];
    const float* a1d = (const float*)d_in[4];
    const float* b1  = (const float*)d_in[5];
    const float* W2  = (const float*)d_in[6];
    const float* a2s = (const float*)d_in[7];
    const float* a2d = (const float*)d_in[8];
    const float* b2  = (const float*)d_in[9];
    const float* W_TL = (const float*)d_in[10]; const float* as_TL = (const float*)d_in[11];
    const float* ad_TL = (const float*)d_in[12]; const float* b_TL = (const float*)d_in[13];
    const float* W_YL = (const float*)d_in[14]; const float* as_YL = (const float*)d_in[15];
    const float* ad_YL = (const float*)d_in[16]; const float* b_YL = (const float*)d_in[17];
    const float* W_TS = (const float*)d_in[18]; const float* as_TS = (const float*)d_in[19];
    const float* ad_TS = (const float*)d_in[20]; const float* b_TS = (const float*)d_in[21];
    const float* W_TZ = (const float*)d_in[22]; const float* as_TZ = (const float*)d_in[23];
    const float* ad_TZ = (const float*)d_in[24]; const float* b_TZ = (const float*)d_in[25];

    const int N = in_sizes[0] / 128;
    const int E = in_sizes[1] / 2;
    const int* e_src = ei;
    const int* e_dst = ei + E;
    const int M4 = E + 4 * N;              // padded CSR slot bound (rows x4)

    float* ws = (float*)d_ws;
    float* B1   = ws;
    float* B2   = B1 + (size_t)N * 256;
    float* B3   = B2 + (size_t)N * 256;
    float* as1  = B3 + (size_t)N * 256;    // N*8
    float* ad1  = as1 + (size_t)N * 8;
    float* as2  = ad1 + (size_t)N * 8;
    float* ad2  = as2 + (size_t)N * 8;
    float* ast  = ad2 + (size_t)N * 8;     // N*4
    float* adt  = ast + (size_t)N * 4;
    float* Wcat = adt + (size_t)N * 4;     // 256*224 (padded task layout)
    float* bcat = Wcat + 256 * 224;        // 224
    float* ascat = bcat + 224;
    float* adcat = ascat + 224;
    int* deg      = (int*)(adcat + 224);   // N
    int* rowstart = deg + N;               // N+1 (cap N+4, keeps csr 16B-aligned)
    int* cursor   = rowstart + (N + 4);    // N
    int* csr      = cursor + N;            // M4 (16B-aligned)
    uintptr_t wsp = (uintptr_t)(csr + M4);
    wsp = (wsp + 15) & ~(uintptr_t)15;
    short* W1h = (short*)wsp;              // 272*128 (256 feat + 16 alpha)
    short* W1l = W1h + 272 * 128;
    short* W2h = W1l + 272 * 128;          // 272*256
    short* W2l = W2h + 272 * 256;
    short* Wth = W2l + 272 * 256;          // 232*256 (224 feat + 8 alpha)
    short* Wtl = Wth + 232 * 256;
    // overlays
    short* Xh  = (short*)B1;               // N*128
    short* Sh  = (short*)B1;               // N*256
    short* Th  = (short*)B1;               // N*256
    short* h1b = (short*)B2;               // stride 256
    short* h2b = (short*)B2;               // stride 256
    short* htb = (short*)B2;               // stride 224

    float* out = (float*)d_out;

    const int B = 256;
    // --- CSR build (padded rows) ---
    init_kernel<<<(N + B - 1) / B, B, 0, stream>>>(deg, cursor, N);
    count_kernel<<<(E + B - 1) / B, B, 0, stream>>>(e_dst, deg, E);
    scan_kernel<<<1, 1024, 0, stream>>>(deg, rowstart, N);
    hipMemsetAsync(csr, 0xFF, (size_t)M4 * sizeof(int), stream);   // csr = -1 (pads)
    scatter_kernel<<<(E + N + B - 1) / B, B, 0, stream>>>(e_src, e_dst, rowstart, cursor, csr, E, N);
    // --- pack + split + fold weights ---
    pack_w_kernel<<<(256 * 224 + B - 1) / B, B, 0, stream>>>(W_TL, W_YL, W_TS, W_TZ,
        b_TL, b_YL, b_TS, b_TZ, as_TL, as_YL, as_TS, as_TZ, ad_TL, ad_YL, ad_TS, ad_TZ,
        Wcat, bcat, ascat, adcat);
    split_bt_kernel<<<(256 * 128 + B - 1) / B, B, 0, stream>>>(W1, W1h, W1l, 128, 256, 7);
    split_bt_kernel<<<(256 * 256 + B - 1) / B, B, 0, stream>>>(W2, W2h, W2l, 256, 256, 8);
    split_bt_kernel<<<(224 * 256 + B - 1) / B, B, 0, stream>>>(Wcat, Wth, Wtl, 256, 224, 8);
    fold_alpha8_kernel<<<(128 * 16 + B - 1) / B, B, 0, stream>>>(W1, a1s, a1d, W1h, W1l, 128, 256);
    fold_alpha8_kernel<<<(256 * 16 + B - 1) / B, B, 0, stream>>>(W2, a2s, a2d, W2h, W2l, 256, 256);
    fold_alpha4_kernel<<<(256 * 8 + B - 1) / B, B, 0, stream>>>(Wcat, ascat, adcat, Wth, Wtl);
    // --- conv1: GEMM emits h1b bf16 + als1/ald1 directly ---
    tobf_kernel<<<((N * 128 / 4) + B - 1) / B, B, 0, stream>>>(x, Xh, N * 128 / 4);
    {
        dim3 g((272 + NB - 1) / NB, (N + MB - 1) / MB);
        gemm_mfma_kernel<<<g, 256, 0, stream>>>(Xh, W1h, W1l, h1b, 256,
                                                as1, ad1, 8, N, 128, 256, 272);
    }
    gat_gather_kernel<<<(N + 3) / 4, 256, 0, stream>>>(h1b, as1, ad1, rowstart, csr, b1, Sh, N, 1);
    // --- conv2 ---
    {
        dim3 g((272 + NB - 1) / NB, (N + MB - 1) / MB);
        gemm_mfma_kernel<<<g, 256, 0, stream>>>(Sh, W2h, W2l, h2b, 256,
                                                as2, ad2, 8, N, 256, 256, 272);
    }
    gat_gather_kernel<<<(N + 3) / 4, 256, 0, stream>>>(h2b, as2, ad2, rowstart, csr, b2, Th, N, 0);
    // --- task heads: GEMM emits htb bf16 (stride 224, padded) + ast/adt ---
    {
        dim3 g((232 + NB - 1) / NB, (N + MB - 1) / MB);
        gemm_mfma_kernel<<<g, 256, 0, stream>>>(Th, Wth, Wtl, htb, 224,
                                                ast, adt, 4, N, 256, 224, 232);
    }
    task_gather_ls_kernel<<<(N + 3) / 4, 256, 0, stream>>>(htb, ast, adt, rowstart, csr, bcat, out, N);
}

// Round 10
// 584.004 us; speedup vs baseline: 1.0115x; 1.0115x over previous
//
#include <hip/hip_runtime.h>
#include <math.h>

// ---------------------------------------------------------------------------
// MultiTaskGAT: 2x GATConv(8 heads x 32ch, concat) + 4 task heads (1 head)
// N=50000 nodes, E=800000 edges (+N self loops), F_IN=128, DH=256.
//
// R4: GEMMs -> bf16 MFMA hi/lo split.
// R6: alphas folded into GEMM B-columns; log_softmax fused into task gather.
// R8: CSR rows padded to x4; shuffle-based scan kernel.
// R9: per-wave CSR index preload (1 coalesced load + v_readlane).
// R11: edge weights fused into gathers (ew kernels/csrd deleted).
// R16: chunk-hoisted edge weights -> per-wave LDS (conflict-free, stride 68).
// R17 (REVERTED loop): 2-deep pipeline cost +12 VGPR -> occupancy 65->49%,
//     task 73.6->81.4. This gather hides latency via TLP; occupancy rules.
// R18: R16 loop exactly (36 VGPR) + R17's direct-LSE epilogue only
//     (drop max-subtraction: logits O(10), f32-exact to tolerance; removes
//     24 shfl_xor + the serialized max->exp chain per wave).
// ---------------------------------------------------------------------------

#define NEG_SLOPE 0.2f

typedef short s8v __attribute__((ext_vector_type(8)));
typedef short s4v __attribute__((ext_vector_type(4)));
typedef float f4v __attribute__((ext_vector_type(4)));

__device__ __forceinline__ short f2bf(float x) {
    unsigned u = __float_as_uint(x);
    u += 0x7fffu + ((u >> 16) & 1u);
    return (short)(u >> 16);
}
__device__ __forceinline__ float bf2f(short b) {
    return __uint_as_float(((unsigned)(unsigned short)b) << 16);
}
__device__ __forceinline__ void split2(float x, short& h, short& l) {
    h = f2bf(x);
    l = f2bf(x - bf2f(h));
}
__device__ __forceinline__ float4 bf4_to_f4(s4v v) {
    return make_float4(bf2f(v[0]), bf2f(v[1]), bf2f(v[2]), bf2f(v[3]));
}
// leaky_relu(x) == max(x, 0.2x) for slope<1
__device__ __forceinline__ float leaky(float x) {
    return fmaxf(x, NEG_SLOPE * x);
}

// ---------------- CSR build ----------------

__global__ void init_kernel(int* __restrict__ deg, int* __restrict__ cursor, int n) {
    int i = blockIdx.x * blockDim.x + threadIdx.x;
    if (i < n) { deg[i] = 1; cursor[i] = 0; }   // deg starts at 1: self loop
}

__global__ void count_kernel(const int* __restrict__ dst, int* __restrict__ deg, int E) {
    int i = blockIdx.x * blockDim.x + threadIdx.x;
    if (i < E) atomicAdd(&deg[dst[i]], 1);
}

// scan of padded degrees ((deg+3)&~3) — shuffle-based, 3 barriers/iter
__global__ __launch_bounds__(1024) void scan_kernel(const int* __restrict__ deg,
                                                    int* __restrict__ rowstart, int n) {
    __shared__ int wsum[16];
    __shared__ int carry_sh;
    int lane = threadIdx.x & 63, wv = threadIdx.x >> 6;
    if (threadIdx.x == 0) { carry_sh = 0; rowstart[0] = 0; }
    __syncthreads();
    for (int base = 0; base < n; base += 8192) {
        int vals[8];
        int sum = 0;
        int i0 = base + threadIdx.x * 8;
        #pragma unroll
        for (int j = 0; j < 8; ++j) {
            int i = i0 + j;
            int v = (i < n) ? ((deg[i] + 3) & ~3) : 0;
            sum += v;
            vals[j] = sum;               // local inclusive
        }
        int incl = sum;
        #pragma unroll
        for (int off = 1; off < 64; off <<= 1) {
            int t = __shfl_up(incl, off);
            if (lane >= off) incl += t;
        }
        if (lane == 63) wsum[wv] = incl;
        __syncthreads();
        if (wv == 0) {
            int s = (lane < 16) ? wsum[lane] : 0;
            #pragma unroll
            for (int off = 1; off < 16; off <<= 1) {
                int t = __shfl_up(s, off);
                if (lane >= off) s += t;
            }
            if (lane < 16) wsum[lane] = s;
        }
        __syncthreads();
        int wexcl = (wv == 0) ? 0 : wsum[wv - 1];
        int excl = carry_sh + wexcl + (incl - sum);
        #pragma unroll
        for (int j = 0; j < 8; ++j) {
            int i = i0 + j;
            if (i < n) rowstart[i + 1] = excl + vals[j];
        }
        __syncthreads();
        if (threadIdx.x == 0) carry_sh += wsum[15];
        __syncthreads();
    }
}

__global__ void scatter_kernel(const int* __restrict__ src, const int* __restrict__ dst,
                               const int* __restrict__ rowstart, int* __restrict__ cursor,
                               int* __restrict__ csr, int E, int n) {
    int i = blockIdx.x * blockDim.x + threadIdx.x;
    if (i >= E + n) return;
    int s, d;
    if (i < E) { s = src[i]; d = dst[i]; }
    else       { s = d = i - E; }          // self loop
    int p = atomicAdd(&cursor[d], 1);
    csr[rowstart[d] + p] = s;
}

// ---------------- bf16 conversions / splits ----------------

__global__ void tobf_kernel(const float* __restrict__ A, short* __restrict__ Ah, int n4) {
    int i = blockIdx.x * blockDim.x + threadIdx.x;
    if (i >= n4) return;
    float4 v = ((const float4*)A)[i];
    s4v hv = {f2bf(v.x), f2bf(v.y), f2bf(v.z), f2bf(v.w)};
    ((s4v*)Ah)[i] = hv;
}

// B[K][Nc] fp32 -> Bt[n][k] bf16 hi/lo (k-contiguous for MFMA B-fragments)
__global__ void split_bt_kernel(const float* __restrict__ B, short* __restrict__ Bh,
                                short* __restrict__ Bl, int K, int Nc, int kshift) {
    int idx = blockIdx.x * blockDim.x + threadIdx.x;
    if (idx >= Nc * K) return;
    int n = idx >> kshift;          // K is a power of two (128/256)
    int k = idx & (K - 1);
    float v = B[(size_t)k * Nc + n];
    short h, l; split2(v, h, l);
    Bh[idx] = h;
    Bl[idx] = l;
}

// fold alphas into extra B-columns: col Nfeat+j (j<8: a_s head j, j>=8: a_d)
__global__ void fold_alpha8_kernel(const float* __restrict__ W,
                                   const float* __restrict__ a_s, const float* __restrict__ a_d,
                                   short* __restrict__ Bth, short* __restrict__ Btl,
                                   int K, int Nfeat) {
    int idx = blockIdx.x * blockDim.x + threadIdx.x;
    if (idx >= K * 16) return;
    int j = idx / K, k = idx % K;
    int h = j & 7;
    const float* av = ((j < 8) ? a_s : a_d) + h * 32;
    const float* wp = W + (size_t)k * 256 + h * 32;
    float s = 0.f;
    #pragma unroll
    for (int c = 0; c < 32; ++c) s += wp[c] * av[c];
    short hi, lo; split2(s, hi, lo);
    size_t off = (size_t)(Nfeat + j) * K + k;
    Bth[off] = hi; Btl[off] = lo;
}

// task version: 4 tasks, PADDED segments over 224 channels, K=256.
// segment starts {0,12,44,104}, padded lengths {12,32,60,120} (pads hold
// zero W and zero alpha -> contribute 0).
__global__ void fold_alpha4_kernel(const float* __restrict__ Wcat,
                                   const float* __restrict__ ascat, const float* __restrict__ adcat,
                                   short* __restrict__ Bth, short* __restrict__ Btl) {
    int idx = blockIdx.x * blockDim.x + threadIdx.x;
    if (idx >= 256 * 8) return;
    int j = idx >> 8, k = idx & 255;
    const int CO[4] = {0, 12, 44, 104};
    const int CL[4] = {12, 32, 60, 120};
    int t = j & 3;
    const float* av = ((j < 4) ? ascat : adcat) + CO[t];
    const float* wp = Wcat + (size_t)k * 224 + CO[t];
    float s = 0.f;
    for (int c = 0; c < CL[t]; ++c) s += wp[c] * av[c];
    short hi, lo; split2(s, hi, lo);
    size_t off = (size_t)(224 + j) * 256 + k;
    Bth[off] = hi; Btl[off] = lo;
}

// ---------------- bf16 MFMA GEMM + fused alpha output ----------------------

#define MB 128
#define NB 64
#define KS 32

__global__ __launch_bounds__(256) void gemm_mfma_kernel(
        const short* __restrict__ Ah_g,
        const short* __restrict__ Bth_g, const short* __restrict__ Btl_g,
        short* __restrict__ Cb, int cb_stride,
        float* __restrict__ als, float* __restrict__ ald, int nsplit,
        int M, int K, int Nfeat, int NcExt) {
    __shared__ __align__(16) short Ah[MB][40];
    __shared__ __align__(16) short Bh[NB][40];
    __shared__ __align__(16) short Bl[NB][40];

    int t = threadIdx.x;
    int lane = t & 63, w = t >> 6;
    int quad = lane >> 4, l16 = lane & 15;
    int row0 = blockIdx.y * MB, col0 = blockIdx.x * NB;

    f4v acc[2][4];
    #pragma unroll
    for (int mt = 0; mt < 2; ++mt)
        #pragma unroll
        for (int nt = 0; nt < 4; ++nt)
            acc[mt][nt] = (f4v){0.f, 0.f, 0.f, 0.f};

    for (int k0 = 0; k0 < K; k0 += KS) {
        __syncthreads();
        #pragma unroll
        for (int i = 0; i < 2; ++i) {
            int u = i * 256 + t;
            int r = u >> 2, kk = (u & 3) * 8;
            int gr = row0 + r;
            s8v vh = {0, 0, 0, 0, 0, 0, 0, 0};
            if (gr < M) vh = *(const s8v*)(Ah_g + (size_t)gr * K + k0 + kk);
            *(s8v*)&Ah[r][kk] = vh;
        }
        {
            int n = t >> 2, kk = (t & 3) * 8;
            int gc = col0 + n;
            s8v vh = {0, 0, 0, 0, 0, 0, 0, 0};
            s8v vl = {0, 0, 0, 0, 0, 0, 0, 0};
            if (gc < NcExt) {
                vh = *(const s8v*)(Bth_g + (size_t)gc * K + k0 + kk);
                vl = *(const s8v*)(Btl_g + (size_t)gc * K + k0 + kk);
            }
            *(s8v*)&Bh[n][kk] = vh;
            *(s8v*)&Bl[n][kk] = vl;
        }
        __syncthreads();

        int kb = quad * 8;
        s8v a_f[2], b_h[4], b_l[4];
        #pragma unroll
        for (int mt = 0; mt < 2; ++mt) {
            int r = w * 32 + mt * 16 + l16;
            a_f[mt] = *(const s8v*)&Ah[r][kb];
        }
        #pragma unroll
        for (int nt = 0; nt < 4; ++nt) {
            int c = nt * 16 + l16;
            b_h[nt] = *(const s8v*)&Bh[c][kb];
            b_l[nt] = *(const s8v*)&Bl[c][kb];
        }
        #pragma unroll
        for (int mt = 0; mt < 2; ++mt)
            #pragma unroll
            for (int nt = 0; nt < 4; ++nt) {
                acc[mt][nt] = __builtin_amdgcn_mfma_f32_16x16x32_bf16(
                    a_f[mt], b_h[nt], acc[mt][nt], 0, 0, 0);
                acc[mt][nt] = __builtin_amdgcn_mfma_f32_16x16x32_bf16(
                    a_f[mt], b_l[nt], acc[mt][nt], 0, 0, 0);
            }
    }

    // epilogue: C/D layout col=lane&15, row=quad*4+reg
    #pragma unroll
    for (int mt = 0; mt < 2; ++mt) {
        #pragma unroll
        for (int nt = 0; nt < 4; ++nt) {
            int gc = col0 + nt * 16 + l16;
            if (gc >= NcExt) continue;
            #pragma unroll
            for (int r = 0; r < 4; ++r) {
                int gr = row0 + w * 32 + mt * 16 + quad * 4 + r;
                if (gr >= M) continue;
                float v = acc[mt][nt][r];
                if (gc < Nfeat) {
                    Cb[(size_t)gr * cb_stride + gc] = f2bf(v);
                } else {
                    int j = gc - Nfeat;
                    if (j < nsplit)            als[(size_t)gr * nsplit + j] = v;
                    else if (j < 2 * nsplit)   ald[(size_t)gr * nsplit + (j - nsplit)] = v;
                }
            }
        }
    }
}

// ---------------- GAT gather (8 heads x 32 ch), one wave per dst -----------
// Chunk-hoisted weights: lane l (holding edge l's src in idxv) computes all
// 8 head weights for its edge (1x32B als row + 8 exp per 64 edges) into a
// per-wave LDS buffer ewl[h][stride 68] (conflict-free). Group loop reads
// its 8 weights with 2 ds_read_b128.

#define EWS 68   // LDS row stride (dwords): conflict-free b128 reads

__global__ __launch_bounds__(256) void gat_gather_kernel(
        const short* __restrict__ hb,
        const float* __restrict__ als, const float* __restrict__ ald,
        const int* __restrict__ rowstart, const int* __restrict__ csr,
        const float* __restrict__ bias, short* __restrict__ oh, int n, int elu) {
    __shared__ __align__(16) float ewl_all[4][8 * EWS];
    int wv   = threadIdx.x >> 6;
    int lane = threadIdx.x & 63;
    float* ewl = ewl_all[wv];
    int wid  = blockIdx.x * 4 + wv;
    if (wid >= n) return;
    int row = rowstart[wid];
    int pdeg = rowstart[wid + 1] - row;
    int hp = lane >> 3;              // consumer head
    int ch = lane * 4;
    const int* cp = csr + row;
    float aldf[8];
    #pragma unroll
    for (int h = 0; h < 8; ++h) aldf[h] = ald[(size_t)wid * 8 + h];

    float4 acc = {0.f, 0.f, 0.f, 0.f};
    float wsum = 0.f;
    for (int base = 0; base < pdeg; base += 64) {
        int cnt = min(pdeg - base, 64);
        int idxv = -1;
        if (lane < cnt) idxv = cp[base + lane];
        {   // produce this chunk's weights: lane l -> edge l, all 8 heads
            int sidx = idxv < 0 ? 0 : idxv;
            float4 a0 = *(const float4*)(als + (size_t)sidx * 8);
            float4 a1 = *(const float4*)(als + (size_t)sidx * 8 + 4);
            float av[8] = {a0.x, a0.y, a0.z, a0.w, a1.x, a1.y, a1.z, a1.w};
            #pragma unroll
            for (int h = 0; h < 8; ++h) {
                float w = __expf(leaky(av[h] + aldf[h]));
                if (idxv < 0) w = 0.f;
                ewl[h * EWS + lane] = w;
            }
        }
        int e = 0;
        for (; e + 8 <= cnt; e += 8) {
            int si[8];
            #pragma unroll
            for (int i = 0; i < 8; ++i) {
                int r = __builtin_amdgcn_readlane(idxv, e + i);
                si[i] = r < 0 ? 0 : r;
            }
            s4v hv[8];
            #pragma unroll
            for (int i = 0; i < 8; ++i)
                hv[i] = *(const s4v*)(hb + (size_t)si[i] * 256 + ch);
            float4 wa = *(const float4*)&ewl[hp * EWS + e];
            float4 wb = *(const float4*)&ewl[hp * EWS + e + 4];
            float w[8] = {wa.x, wa.y, wa.z, wa.w, wb.x, wb.y, wb.z, wb.w};
            #pragma unroll
            for (int i = 0; i < 8; ++i) {
                float4 h = bf4_to_f4(hv[i]);
                acc.x += w[i] * h.x; acc.y += w[i] * h.y;
                acc.z += w[i] * h.z; acc.w += w[i] * h.w;
                wsum += w[i];
            }
        }
        if (e < cnt) {                   // 4-edge tail, at most once
            int si[4];
            #pragma unroll
            for (int i = 0; i < 4; ++i) {
                int r = __builtin_amdgcn_readlane(idxv, e + i);
                si[i] = r < 0 ? 0 : r;
            }
            s4v hv[4];
            #pragma unroll
            for (int i = 0; i < 4; ++i)
                hv[i] = *(const s4v*)(hb + (size_t)si[i] * 256 + ch);
            float4 wa = *(const float4*)&ewl[hp * EWS + e];
            float w[4] = {wa.x, wa.y, wa.z, wa.w};
            #pragma unroll
            for (int i = 0; i < 4; ++i) {
                float4 h = bf4_to_f4(hv[i]);
                acc.x += w[i] * h.x; acc.y += w[i] * h.y;
                acc.z += w[i] * h.z; acc.w += w[i] * h.w;
                wsum += w[i];
            }
        }
    }
    float inv = 1.f / (wsum + 1e-16f);
    float4 b4 = *(const float4*)(bias + ch);
    float v[4] = {acc.x * inv + b4.x, acc.y * inv + b4.y,
                  acc.z * inv + b4.z, acc.w * inv + b4.w};
    if (elu) {
        #pragma unroll
        for (int j = 0; j < 4; ++j)
            v[j] = (v[j] > 0.f) ? v[j] : __expf(v[j]) - 1.f;
    }
    s4v hvo = {f2bf(v[0]), f2bf(v[1]), f2bf(v[2]), f2bf(v[3])};
    *(s4v*)(oh + (size_t)wid * 256 + ch) = hvo;
}

// ---------------- task-head packing (Wcat, bcat, ascat, adcat) -------------
// PADDED 224-channel layout: segments at {0,12,44,104}, pad cols 42,43 zero.

__global__ void pack_w_kernel(const float* __restrict__ wTL, const float* __restrict__ wYL,
                              const float* __restrict__ wTS, const float* __restrict__ wTZ,
                              const float* __restrict__ bTL, const float* __restrict__ bYL,
                              const float* __restrict__ bTS, const float* __restrict__ bTZ,
                              const float* __restrict__ asTL, const float* __restrict__ asYL,
                              const float* __restrict__ asTS, const float* __restrict__ asTZ,
                              const float* __restrict__ adTL, const float* __restrict__ adYL,
                              const float* __restrict__ adTS, const float* __restrict__ adTZ,
                              float* __restrict__ Wcat, float* __restrict__ bcat,
                              float* __restrict__ ascat, float* __restrict__ adcat) {
    int idx = blockIdx.x * blockDim.x + threadIdx.x;
    if (idx < 256 * 224) {
        int r = idx / 224, c = idx % 224;
        float v = 0.f;
        if (c < 12)       v = wTL[r * 12 + c];
        else if (c < 42)  v = wYL[r * 30 + (c - 12)];
        else if (c < 44)  v = 0.f;
        else if (c < 104) v = wTS[r * 60 + (c - 44)];
        else              v = wTZ[r * 120 + (c - 104)];
        Wcat[idx] = v;
    }
    if (idx < 224) {
        float b = 0.f, as_ = 0.f, ad_ = 0.f;
        if (idx < 12)       { b = bTL[idx];       as_ = asTL[idx];       ad_ = adTL[idx]; }
        else if (idx < 42)  { b = bYL[idx - 12];  as_ = asYL[idx - 12];  ad_ = adYL[idx - 12]; }
        else if (idx < 44)  { }
        else if (idx < 104) { b = bTS[idx - 44];  as_ = asTS[idx - 44];  ad_ = adTS[idx - 44]; }
        else                { b = bTZ[idx - 104]; as_ = asTZ[idx - 104]; ad_ = adTZ[idx - 104]; }
        bcat[idx]  = b;
        ascat[idx] = as_;
        adcat[idx] = ad_;
    }
}

// ---------------- 4-task gather + fused log_softmax (register-only) --------
// Padded 224-ch layout: lane*4 channels lie in exactly ONE task segment.
// Chunk-hoisted LDS weights (R16 loop). Direct LSE (no max-subtraction).

__device__ __forceinline__ float sel4(int t, float v0, float v1, float v2, float v3) {
    return (t == 0) ? v0 : (t == 1) ? v1 : (t == 2) ? v2 : v3;
}

__global__ __launch_bounds__(256) void task_gather_ls_kernel(
        const short* __restrict__ htb,
        const float* __restrict__ ast, const float* __restrict__ adt,
        const int* __restrict__ rowstart, const int* __restrict__ csr,
        const float* __restrict__ bcat, float* __restrict__ out, int n) {
    __shared__ __align__(16) float ewl_all[4][4 * EWS];
    int wv   = threadIdx.x >> 6;
    int lane = threadIdx.x & 63;
    float* ewl = ewl_all[wv];
    int wid  = blockIdx.x * 4 + wv;
    if (wid >= n) return;
    int row = rowstart[wid];
    int pdeg = rowstart[wid + 1] - row;
    int ch0 = (lane < 56) ? lane * 4 : 0;
    int t = (lane < 3) ? 0 : (lane < 11) ? 1 : (lane < 26) ? 2 : 3;
    int COp = (t == 0) ? 0 : (t == 1) ? 12 : (t == 2) ? 44 : 104;   // padded start
    int COr = (t == 0) ? 0 : (t == 1) ? 12 : (t == 2) ? 42 : 102;   // real out offset
    int CLr = (t == 0) ? 12 : (t == 1) ? 30 : (t == 2) ? 60 : 120;  // real length
    bool valj[4];
    #pragma unroll
    for (int j = 0; j < 4; ++j)
        valj[j] = (unsigned)(ch0 + j - COp) < (unsigned)CLr;

    const int* cp = csr + row;
    float adtf[4];
    #pragma unroll
    for (int q = 0; q < 4; ++q) adtf[q] = adt[(size_t)wid * 4 + q];

    float acc[4] = {0.f, 0.f, 0.f, 0.f};
    float wsv = 0.f;
    for (int base = 0; base < pdeg; base += 64) {
        int cnt = min(pdeg - base, 64);
        int idxv = -1;
        if (lane < cnt) idxv = cp[base + lane];
        {   // produce this chunk's weights: lane l -> edge l, all 4 tasks
            int sidx = idxv < 0 ? 0 : idxv;
            float4 a = *(const float4*)(ast + (size_t)sidx * 4);
            float av[4] = {a.x, a.y, a.z, a.w};
            #pragma unroll
            for (int q = 0; q < 4; ++q) {
                float w = __expf(leaky(av[q] + adtf[q]));
                if (idxv < 0) w = 0.f;
                ewl[q * EWS + lane] = w;
            }
        }
        int e = 0;
        for (; e + 8 <= cnt; e += 8) {
            int si[8];
            #pragma unroll
            for (int i = 0; i < 8; ++i) {
                int r = __builtin_amdgcn_readlane(idxv, e + i);
                si[i] = r < 0 ? 0 : r;
            }
            s4v hv[8];
            #pragma unroll
            for (int i = 0; i < 8; ++i)
                hv[i] = *(const s4v*)(htb + (size_t)si[i] * 224 + ch0);
            float4 wa = *(const float4*)&ewl[t * EWS + e];
            float4 wb = *(const float4*)&ewl[t * EWS + e + 4];
            float w[8] = {wa.x, wa.y, wa.z, wa.w, wb.x, wb.y, wb.z, wb.w};
            #pragma unroll
            for (int i = 0; i < 8; ++i) {
                float4 h = bf4_to_f4(hv[i]);
                acc[0] += w[i] * h.x; acc[1] += w[i] * h.y;
                acc[2] += w[i] * h.z; acc[3] += w[i] * h.w;
                wsv += w[i];
            }
        }
        if (e < cnt) {                   // 4-edge tail, at most once
            int si[4];
            #pragma unroll
            for (int i = 0; i < 4; ++i) {
                int r = __builtin_amdgcn_readlane(idxv, e + i);
                si[i] = r < 0 ? 0 : r;
            }
            s4v hv[4];
            #pragma unroll
            for (int i = 0; i < 4; ++i)
                hv[i] = *(const s4v*)(htb + (size_t)si[i] * 224 + ch0);
            float4 wa = *(const float4*)&ewl[t * EWS + e];
            float w[4] = {wa.x, wa.y, wa.z, wa.w};
            #pragma unroll
            for (int i = 0; i < 4; ++i) {
                float4 h = bf4_to_f4(hv[i]);
                acc[0] += w[i] * h.x; acc[1] += w[i] * h.y;
                acc[2] += w[i] * h.z; acc[3] += w[i] * h.w;
                wsv += w[i];
            }
        }
    }
    float inv = 1.f / (wsv + 1e-16f);

    // normalized logits; direct LSE (no max-subtraction)
    float vout[4];
    float sacc = 0.f;
    #pragma unroll
    for (int j = 0; j < 4; ++j) {
        float v = 0.f;
        if (valj[j]) { v = acc[j] * inv + bcat[ch0 + j]; sacc += __expf(v); }
        vout[j] = v;
    }
    float s0 = (t == 0) ? sacc : 0.f;
    float s1 = (t == 1) ? sacc : 0.f;
    float s2 = (t == 2) ? sacc : 0.f;
    float s3 = (t == 3) ? sacc : 0.f;
    #pragma unroll
    for (int off = 1; off < 64; off <<= 1) {
        s0 += __shfl_xor(s0, off);
        s1 += __shfl_xor(s1, off);
        s2 += __shfl_xor(s2, off);
        s3 += __shfl_xor(s3, off);
    }
    float st = sel4(t, s0, s1, s2, s3);
    float lse = __logf(st);
    #pragma unroll
    for (int j = 0; j < 4; ++j)
        if (valj[j])
            out[(size_t)COr * n + (size_t)wid * CLr + (ch0 + j - COp)] = vout[j] - lse;
}

// ---------------- launcher ----------------

extern "C" void kernel_launch(void* const* d_in, const int* in_sizes, int n_in,
                              void* d_out, int out_size, void* d_ws, size_t ws_size,
                              hipStream_t stream) {
    const float* x   = (const float*)d_in[0];
    const int*   ei  = (const int*)d_in[1];
    const float* W1  = (const float*)d_in[2];
    const float* a1s = (const float*)d_in[3];
    const float* a1d = (const float*)d_in[4];
    const float* b1  = (const float*)d_in[5];
    const float* W2  = (const float*)d_in[6];
    const float* a2s = (const float*)d_in[7];
    const float* a2d = (const float*)d_in[8];
    const float* b2  = (const float*)d_in[9];
    const float* W_TL = (const float*)d_in[10]; const float* as_TL = (const float*)d_in[11];
    const float* ad_TL = (const float*)d_in[12]; const float* b_TL = (const float*)d_in[13];
    const float* W_YL = (const float*)d_in[14]; const float* as_YL = (const float*)d_in[15];
    const float* ad_YL = (const float*)d_in[16]; const float* b_YL = (const float*)d_in[17];
    const float* W_TS = (const float*)d_in[18]; const float* as_TS = (const float*)d_in[19];
    const float* ad_TS = (const float*)d_in[20]; const float* b_TS = (const float*)d_in[21];
    const float* W_TZ = (const float*)d_in[22]; const float* as_TZ = (const float*)d_in[23];
    const float* ad_TZ = (const float*)d_in[24]; const float* b_TZ = (const float*)d_in[25];

    const int N = in_sizes[0] / 128;
    const int E = in_sizes[1] / 2;
    const int* e_src = ei;
    const int* e_dst = ei + E;
    const int M4 = E + 4 * N;              // padded CSR slot bound (rows x4)

    float* ws = (float*)d_ws;
    float* B1   = ws;
    float* B2   = B1 + (size_t)N * 256;
    float* B3   = B2 + (size_t)N * 256;
    float* as1  = B3 + (size_t)N * 256;    // N*8
    float* ad1  = as1 + (size_t)N * 8;
    float* as2  = ad1 + (size_t)N * 8;
    float* ad2  = as2 + (size_t)N * 8;
    float* ast  = ad2 + (size_t)N * 8;     // N*4
    float* adt  = ast + (size_t)N * 4;
    float* Wcat = adt + (size_t)N * 4;     // 256*224 (padded task layout)
    float* bcat = Wcat + 256 * 224;        // 224
    float* ascat = bcat + 224;
    float* adcat = ascat + 224;
    int* deg      = (int*)(adcat + 224);   // N
    int* rowstart = deg + N;               // N+1 (cap N+4, keeps csr 16B-aligned)
    int* cursor   = rowstart + (N + 4);    // N
    int* csr      = cursor + N;            // M4 (16B-aligned)
    uintptr_t wsp = (uintptr_t)(csr + M4);
    wsp = (wsp + 15) & ~(uintptr_t)15;
    short* W1h = (short*)wsp;              // 272*128 (256 feat + 16 alpha)
    short* W1l = W1h + 272 * 128;
    short* W2h = W1l + 272 * 128;          // 272*256
    short* W2l = W2h + 272 * 256;
    short* Wth = W2l + 272 * 256;          // 232*256 (224 feat + 8 alpha)
    short* Wtl = Wth + 232 * 256;
    // overlays
    short* Xh  = (short*)B1;               // N*128
    short* Sh  = (short*)B1;               // N*256
    short* Th  = (short*)B1;               // N*256
    short* h1b = (short*)B2;               // stride 256
    short* h2b = (short*)B2;               // stride 256
    short* htb = (short*)B2;               // stride 224

    float* out = (float*)d_out;

    const int B = 256;
    // --- CSR build (padded rows) ---
    init_kernel<<<(N + B - 1) / B, B, 0, stream>>>(deg, cursor, N);
    count_kernel<<<(E + B - 1) / B, B, 0, stream>>>(e_dst, deg, E);
    scan_kernel<<<1, 1024, 0, stream>>>(deg, rowstart, N);
    hipMemsetAsync(csr, 0xFF, (size_t)M4 * sizeof(int), stream);   // csr = -1 (pads)
    scatter_kernel<<<(E + N + B - 1) / B, B, 0, stream>>>(e_src, e_dst, rowstart, cursor, csr, E, N);
    // --- pack + split + fold weights ---
    pack_w_kernel<<<(256 * 224 + B - 1) / B, B, 0, stream>>>(W_TL, W_YL, W_TS, W_TZ,
        b_TL, b_YL, b_TS, b_TZ, as_TL, as_YL, as_TS, as_TZ, ad_TL, ad_YL, ad_TS, ad_TZ,
        Wcat, bcat, ascat, adcat);
    split_bt_kernel<<<(256 * 128 + B - 1) / B, B, 0, stream>>>(W1, W1h, W1l, 128, 256, 7);
    split_bt_kernel<<<(256 * 256 + B - 1) / B, B, 0, stream>>>(W2, W2h, W2l, 256, 256, 8);
    split_bt_kernel<<<(224 * 256 + B - 1) / B, B, 0, stream>>>(Wcat, Wth, Wtl, 256, 224, 8);
    fold_alpha8_kernel<<<(128 * 16 + B - 1) / B, B, 0, stream>>>(W1, a1s, a1d, W1h, W1l, 128, 256);
    fold_alpha8_kernel<<<(256 * 16 + B - 1) / B, B, 0, stream>>>(W2, a2s, a2d, W2h, W2l, 256, 256);
    fold_alpha4_kernel<<<(256 * 8 + B - 1) / B, B, 0, stream>>>(Wcat, ascat, adcat, Wth, Wtl);
    // --- conv1: GEMM emits h1b bf16 + als1/ald1 directly ---
    tobf_kernel<<<((N * 128 / 4) + B - 1) / B, B, 0, stream>>>(x, Xh, N * 128 / 4);
    {
        dim3 g((272 + NB - 1) / NB, (N + MB - 1) / MB);
        gemm_mfma_kernel<<<g, 256, 0, stream>>>(Xh, W1h, W1l, h1b, 256,
                                                as1, ad1, 8, N, 128, 256, 272);
    }
    gat_gather_kernel<<<(N + 3) / 4, 256, 0, stream>>>(h1b, as1, ad1, rowstart, csr, b1, Sh, N, 1);
    // --- conv2 ---
    {
        dim3 g((272 + NB - 1) / NB, (N + MB - 1) / MB);
        gemm_mfma_kernel<<<g, 256, 0, stream>>>(Sh, W2h, W2l, h2b, 256,
                                                as2, ad2, 8, N, 256, 256, 272);
    }
    gat_gather_kernel<<<(N + 3) / 4, 256, 0, stream>>>(h2b, as2, ad2, rowstart, csr, b2, Th, N, 0);
    // --- task heads: GEMM emits htb bf16 (stride 224, padded) + ast/adt ---
    {
        dim3 g((232 + NB - 1) / NB, (N + MB - 1) / MB);
        gemm_mfma_kernel<<<g, 256, 0, stream>>>(Th, Wth, Wtl, htb, 224,
                                                ast, adt, 4, N, 256, 224, 232);
    }
    task_gather_ls_kernel<<<(N + 3) / 4, 256, 0, stream>>>(htb, ast, adt, rowstart, csr, bcat, out, N);
}